// Round 6
// baseline (513.108 us; speedup 1.0000x reference)
//
#include <hip/hip_runtime.h>

typedef unsigned int u32;
typedef unsigned short u16;
typedef __attribute__((ext_vector_type(4))) float f32x4;
typedef __attribute__((ext_vector_type(4))) int i32x4;
typedef __attribute__((ext_vector_type(2))) int i32x2;
typedef __attribute__((ext_vector_type(8))) short s16x8;

#define N_NODES 8192
#define F_DIM 512

#define BARRIER_NOVM() asm volatile("s_waitcnt lgkmcnt(0)\ns_barrier" ::: "memory")

__device__ __forceinline__ int fm_swz(int m) {
    return ((m >> 2) & 7) ^ ((m & 3) << 1);
}

__device__ __forceinline__ u16 f2bf(float x) {
    u32 u = __builtin_bit_cast(u32, x);
    u = (u + 0x7FFFu + ((u >> 16) & 1u)) >> 16;
    return (u16)u;
}

__device__ __forceinline__ float bf2f(u16 b) {
    u32 u = ((u32)b) << 16;
    return __builtin_bit_cast(float, u);
}

__device__ __forceinline__ void glds16(const u16* g, u16* l) {
    __builtin_amdgcn_global_load_lds((const __attribute__((address_space(1))) u32*)g,
                                     (__attribute__((address_space(3))) u32*)l, 16, 0, 0);
}

// k0 transpose-tile swizzle: physical 16B-slot for (row, logical slot).
// Spreads any 64-lane access over all 8 bank-quads (verified 8x each = optimal).
__device__ __forceinline__ int t_swz(int row, int slot) {
    return ((slot + (row >> 3)) ^ (row & 7)) & 15;
}

// ---------------- kZ: zero deg[8192] ----------------
__global__ __launch_bounds__(256) void kZ(int* __restrict__ deg) {
    i32x4 z = {0, 0, 0, 0};
    *(i32x4*)(deg + blockIdx.x * 1024 + threadIdx.x * 4) = z;
}

// ---------------- kM: merged adj-transpose (blocks 0..4095) + X@W (blocks 4096..4351) ----------------
__global__ __launch_bounds__(256, 4)
void kM(const int* __restrict__ adj, const float* __restrict__ X, const float* __restrict__ W,
        u16* __restrict__ At, u16* __restrict__ Yt, int* __restrict__ deg) {
    __shared__ __align__(16) u16 SH[16384 + 1024];  // 34 KB overlay

    const int tid = threadIdx.x;

    if (blockIdx.x < 4096) {
        // ---- k0: At[j][i] = bf16(adj[i][j]); deg[j] += column sums ----
        u16* T = SH;                       // 128 x (16 slots of 16B)
        int (*Dred)[128] = (int(*)[128])(SH + 16384);

        const int i0 = (blockIdx.x & 63) * 128;
        const int j0 = (blockIdx.x >> 6) * 128;
        const int jj = (tid & 63) * 2;  // two consecutive j rows
        const int ih = tid >> 6;        // i-chunk of 32

        u32 pk[2][16];
        int d0 = 0, d1 = 0;
        const int* ap = adj + (size_t)(i0 + ih * 32) * N_NODES + j0 + jj;
#pragma unroll
        for (int r = 0; r < 32; ++r) {
            i32x2 v = *(const i32x2*)ap;
            ap += N_NODES;
            d0 += v[0]; d1 += v[1];
            u32 b0 = (u32)v[0] * 0x3F80u;
            u32 b1 = (u32)v[1] * 0x3F80u;
            if ((r & 1) == 0) { pk[0][r >> 1] = b0;        pk[1][r >> 1] = b1; }
            else              { pk[0][r >> 1] |= b0 << 16; pk[1][r >> 1] |= b1 << 16; }
        }
#pragma unroll
        for (int p = 0; p < 2; ++p) {
            int row = jj + p;
#pragma unroll
            for (int c = 0; c < 4; ++c) {
                int ps = t_swz(row, ih * 4 + c);
                i32x4 w = {(int)pk[p][c * 4], (int)pk[p][c * 4 + 1],
                           (int)pk[p][c * 4 + 2], (int)pk[p][c * 4 + 3]};
                *(i32x4*)&T[row * 128 + ps * 8] = w;
            }
        }
        Dred[ih][jj] = d0;
        Dred[ih][jj + 1] = d1;
        __syncthreads();

#pragma unroll
        for (int rep = 0; rep < 8; ++rep) {
            int row = (tid >> 4) + rep * 16;
            int slot = tid & 15;
            int ps = t_swz(row, slot);
            i32x4 w = *(const i32x4*)&T[row * 128 + ps * 8];
            *(i32x4*)(At + (size_t)(j0 + row) * N_NODES + i0 + slot * 8) = w;
        }
        if (tid < 128) {
            int d = Dred[0][tid] + Dred[1][tid] + Dred[2][tid] + Dred[3][tid];
            atomicAdd(&deg[j0 + tid], d);
        }
        return;
    }

    // ---- k1: Yt[f][i] = bf16( sum_c W[c][f] * X[i][c] ) ----
    u16* Wl = SH;          // 128 x 64
    u16* Xl = SH + 8192;   // 128 x 64

    const int bid = blockIdx.x - 4096;
    const int lane = tid & 63;
    const int wave = tid >> 6;
    const int wm = wave >> 1, wn = wave & 1;
    const int col = lane & 15, quad = lane >> 4;

    const int f0 = (bid & 3) * 128;
    const int i0 = (bid >> 2) * 128;

    const int cgrp = tid & 31;
    const int kk   = tid >> 5;
    const int xcq  = tid & 15;
    const int xig  = tid >> 4;

    f32x4 wr[8], xr[8];
    {
        const float* wp = W + (size_t)(kk * 8) * F_DIM + f0 + cgrp * 4;
        const float* xp = X + (size_t)(i0 + xig * 8) * F_DIM + xcq * 4;
#pragma unroll
        for (int r = 0; r < 8; ++r) wr[r] = *(const f32x4*)(wp + (size_t)r * F_DIM);
#pragma unroll
        for (int r = 0; r < 8; ++r) xr[r] = *(const f32x4*)(xp + (size_t)r * F_DIM);
    }

    f32x4 acc[4][4] = {};

    for (int s = 0; s < 8; ++s) {
        BARRIER_NOVM();
#pragma unroll
        for (int mm = 0; mm < 4; ++mm) {
            int m = cgrp * 4 + mm;
            u32 q0 = ((u32)f2bf(wr[1][mm]) << 16) | f2bf(wr[0][mm]);
            u32 q1 = ((u32)f2bf(wr[3][mm]) << 16) | f2bf(wr[2][mm]);
            u32 q2 = ((u32)f2bf(wr[5][mm]) << 16) | f2bf(wr[4][mm]);
            u32 q3 = ((u32)f2bf(wr[7][mm]) << 16) | f2bf(wr[6][mm]);
            i32x4 v = {(int)q0, (int)q1, (int)q2, (int)q3};
            *(i32x4*)&Wl[m * 64 + ((kk ^ fm_swz(m)) << 3)] = v;
        }
#pragma unroll
        for (int r = 0; r < 8; ++r) {
            int row = xig * 8 + r;
            u32 a = ((u32)f2bf(xr[r][1]) << 16) | f2bf(xr[r][0]);
            u32 b = ((u32)f2bf(xr[r][3]) << 16) | f2bf(xr[r][2]);
            int kc = xcq >> 1, half = xcq & 1;
            i32x2 v = {(int)a, (int)b};
            *(i32x2*)&Xl[row * 64 + ((kc ^ (row & 7)) << 3) + half * 4] = v;
        }
        BARRIER_NOVM();
        if (s + 1 < 8) {
            int c0 = (s + 1) * 64;
            const float* wp = W + (size_t)(c0 + kk * 8) * F_DIM + f0 + cgrp * 4;
            const float* xp = X + (size_t)(i0 + xig * 8) * F_DIM + c0 + xcq * 4;
#pragma unroll
            for (int r = 0; r < 8; ++r) wr[r] = *(const f32x4*)(wp + (size_t)r * F_DIM);
#pragma unroll
            for (int r = 0; r < 8; ++r) xr[r] = *(const f32x4*)(xp + (size_t)r * F_DIM);
        }
#pragma unroll
        for (int s2 = 0; s2 < 2; ++s2) {
            s16x8 af[4], bfr[4];
#pragma unroll
            for (int mi = 0; mi < 4; ++mi) {
                int m = wm * 64 + mi * 16 + col;
                int kc = s2 * 4 + quad;
                af[mi] = *(const s16x8*)&Wl[m * 64 + ((kc ^ fm_swz(m)) << 3)];
            }
#pragma unroll
            for (int ni = 0; ni < 4; ++ni) {
                int rr = wn * 64 + ni * 16 + col;
                int kc = s2 * 4 + quad;
                bfr[ni] = *(const s16x8*)&Xl[rr * 64 + ((kc ^ (rr & 7)) << 3)];
            }
#pragma unroll
            for (int mi = 0; mi < 4; ++mi)
#pragma unroll
                for (int ni = 0; ni < 4; ++ni)
                    acc[mi][ni] = __builtin_amdgcn_mfma_f32_16x16x32_bf16(af[mi], bfr[ni],
                                                                          acc[mi][ni], 0, 0, 0);
        }
    }

#pragma unroll
    for (int mi = 0; mi < 4; ++mi)
#pragma unroll
        for (int r = 0; r < 4; ++r) {
            int f = f0 + wm * 64 + mi * 16 + quad * 4 + r;
#pragma unroll
            for (int ni = 0; ni < 4; ++ni) {
                int i = i0 + wn * 64 + ni * 16 + col;
                Yt[(size_t)f * N_NODES + i] = f2bf(acc[mi][ni][r]);
            }
        }
}

// ---------------- Kernel 2: bf16 GEMM (m97 clone): parts[kq][j][f] = sum adjT*Yt (bf16 out) ----------------
// 128x128 tile, BK=64, single-buffered 32 KB LDS, 2-barrier K-loop, K-split 4 -> 4 blocks/CU.
__global__ __launch_bounds__(256, 4)
void k2_gemm(const u16* __restrict__ At, const u16* __restrict__ Yt,
             u16* __restrict__ parts) {
    __shared__ __align__(16) u16 As[128 * 64];
    __shared__ __align__(16) u16 Bs[128 * 64];

    const int tid = threadIdx.x, lane = tid & 63, wave = tid >> 6;
    const int wm = wave >> 1, wn = wave & 1;
    const int col = lane & 15, quad = lane >> 4;

    // bid = f_idx*256 + kq*64 + stripe: all 16 (f,kq) blocks of a stripe share bid%8 (XCD L2)
    const int f_idx = blockIdx.x >> 8;
    const int kq = (blockIdx.x >> 6) & 3;
    const int stripe = blockIdx.x & 63;
    const int j0 = stripe * 128, f0 = f_idx * 128, ibase = kq * 2048;
    u16* __restrict__ part = parts + (size_t)kq * N_NODES * F_DIM;

    const int rowl = lane >> 3;
    const int kc = (lane & 7) ^ rowl;

    f32x4 acc[4][4] = {};

    for (int s = 0; s < 32; ++s) {
        const int ik = ibase + s * 64;
#pragma unroll
        for (int gg = 0; gg < 4; ++gg) {
            const int g = wave * 4 + gg;
            glds16(At + (size_t)(j0 + g * 8 + rowl) * N_NODES + ik + kc * 8, &As[g * 512]);
            glds16(Yt + (size_t)(f0 + g * 8 + rowl) * N_NODES + ik + kc * 8, &Bs[g * 512]);
        }
        __syncthreads();
#pragma unroll
        for (int s2 = 0; s2 < 2; ++s2) {
            s16x8 af[4], bfr[4];
#pragma unroll
            for (int mi = 0; mi < 4; ++mi) {
                int m = wm * 64 + mi * 16 + col;
                int k2i = s2 * 4 + quad;
                af[mi] = *(const s16x8*)&As[m * 64 + ((k2i ^ (m & 7)) << 3)];
            }
#pragma unroll
            for (int ni = 0; ni < 4; ++ni) {
                int rr = wn * 64 + ni * 16 + col;
                int k2i = s2 * 4 + quad;
                bfr[ni] = *(const s16x8*)&Bs[rr * 64 + ((k2i ^ (rr & 7)) << 3)];
            }
#pragma unroll
            for (int mi = 0; mi < 4; ++mi)
#pragma unroll
                for (int ni = 0; ni < 4; ++ni)
                    acc[mi][ni] = __builtin_amdgcn_mfma_f32_16x16x32_bf16(af[mi], bfr[ni],
                                                                          acc[mi][ni], 0, 0, 0);
        }
        __syncthreads();
    }

#pragma unroll
    for (int mi = 0; mi < 4; ++mi)
#pragma unroll
        for (int r = 0; r < 4; ++r) {
            int jl = wm * 64 + mi * 16 + quad * 4 + r;
            size_t ob = (size_t)(j0 + jl) * F_DIM + f0 + wn * 64;
#pragma unroll
            for (int ni = 0; ni < 4; ++ni)
                part[ob + ni * 16 + col] = f2bf(acc[mi][ni][r]);
        }
}

// ---------------- Kernel 3: out = relu( rsqrt(max(deg,1)) * sum4(parts) ) ----------------
__global__ __launch_bounds__(256, 4)
void k3b(const u16* __restrict__ parts, const int* __restrict__ deg,
         float* __restrict__ out) {
    int idx = blockIdx.x * 256 + threadIdx.x;  // 8 f per thread
    int j = idx >> 6;
    int c = (idx & 63) * 8;
    size_t off = (size_t)j * F_DIM + c;
    const size_t PS = (size_t)N_NODES * F_DIM;
    s16x8 a = *(const s16x8*)(parts + off);
    s16x8 b = *(const s16x8*)(parts + PS + off);
    s16x8 cc = *(const s16x8*)(parts + 2 * PS + off);
    s16x8 d = *(const s16x8*)(parts + 3 * PS + off);
    float nv = rsqrtf(fmaxf((float)deg[j], 1.0f));
    f32x4 v0, v1;
#pragma unroll
    for (int t = 0; t < 4; ++t) {
        float s = bf2f((u16)a[t]) + bf2f((u16)b[t]) + bf2f((u16)cc[t]) + bf2f((u16)d[t]);
        v0[t] = fmaxf(s * nv, 0.0f);
    }
#pragma unroll
    for (int t = 0; t < 4; ++t) {
        float s = bf2f((u16)a[4 + t]) + bf2f((u16)b[4 + t]) + bf2f((u16)cc[4 + t]) + bf2f((u16)d[4 + t]);
        v1[t] = fmaxf(s * nv, 0.0f);
    }
    *(f32x4*)(out + off) = v0;
    *(f32x4*)(out + off + 4) = v1;
}

extern "C" void kernel_launch(void* const* d_in, const int* in_sizes, int n_in,
                              void* d_out, int out_size, void* d_ws, size_t ws_size,
                              hipStream_t stream) {
    (void)in_sizes; (void)n_in; (void)out_size; (void)ws_size;
    const float* X = (const float*)d_in[0];
    const int* adj = (const int*)d_in[1];
    const float* W = (const float*)d_in[2];
    float* out = (float*)d_out;
    char* w = (char*)d_ws;

    // ws: At 128Mi | Yt 8Mi | parts(bf16 x4) 32Mi | deg 32K   (~168 MB)
    u16* At = (u16*)w;
    u16* Yt = (u16*)(w + ((size_t)128 << 20));
    u16* parts = (u16*)(w + ((size_t)136 << 20));
    int* deg = (int*)(w + ((size_t)168 << 20));

    kZ<<<dim3(8), dim3(256), 0, stream>>>(deg);
    kM<<<dim3(4352), dim3(256), 0, stream>>>(adj, X, W, At, Yt, deg);
    k2_gemm<<<dim3(1024), dim3(256), 0, stream>>>(At, Yt, parts);
    k3b<<<dim3(2048), dim3(256), 0, stream>>>(parts, deg, out);
}

// Round 7
// 512.263 us; speedup vs baseline: 1.0016x; 1.0016x over previous
//
#include <hip/hip_runtime.h>

typedef unsigned int u32;
typedef unsigned short u16;
typedef __attribute__((ext_vector_type(4))) float f32x4;
typedef __attribute__((ext_vector_type(4))) int i32x4;
typedef __attribute__((ext_vector_type(2))) int i32x2;
typedef __attribute__((ext_vector_type(8))) short s16x8;

#define N_NODES 8192
#define F_DIM 512

#define BARRIER_NOVM() asm volatile("s_waitcnt lgkmcnt(0)\ns_barrier" ::: "memory")

__device__ __forceinline__ int fm_swz(int m) {
    return ((m >> 2) & 7) ^ ((m & 3) << 1);
}

__device__ __forceinline__ u16 f2bf(float x) {
    u32 u = __builtin_bit_cast(u32, x);
    u = (u + 0x7FFFu + ((u >> 16) & 1u)) >> 16;
    return (u16)u;
}

__device__ __forceinline__ float bf2f(u16 b) {
    u32 u = ((u32)b) << 16;
    return __builtin_bit_cast(float, u);
}

__device__ __forceinline__ void glds16(const u16* g, u16* l) {
    __builtin_amdgcn_global_load_lds((const __attribute__((address_space(1))) u32*)g,
                                     (__attribute__((address_space(3))) u32*)l, 16, 0, 0);
}

// k0 transpose-tile swizzle: physical 16B-slot for (row, logical slot).
// Spreads any 64-lane access over all 8 bank-quads (verified 8x each = optimal).
__device__ __forceinline__ int t_swz(int row, int slot) {
    return ((slot + (row >> 3)) ^ (row & 7)) & 15;
}

// ---------------- kZ: zero deg[8192] ----------------
__global__ __launch_bounds__(256) void kZ(int* __restrict__ deg) {
    i32x4 z = {0, 0, 0, 0};
    *(i32x4*)(deg + blockIdx.x * 1024 + threadIdx.x * 4) = z;
}

// ---------------- kM: merged adj-transpose (blocks 0..4095) + X@W (blocks 4096..4351) ----------------
__global__ __launch_bounds__(256, 4)
void kM(const int* __restrict__ adj, const float* __restrict__ X, const float* __restrict__ W,
        u16* __restrict__ At, u16* __restrict__ Yt, int* __restrict__ deg) {
    __shared__ __align__(16) u16 SH[16384 + 1024];  // 34 KB overlay

    const int tid = threadIdx.x;

    if (blockIdx.x < 4096) {
        // ---- k0: At[j][i] = bf16(adj[i][j]); deg[j] += column sums ----
        u16* T = SH;                       // 128 x (16 slots of 16B)
        int (*Dred)[128] = (int(*)[128])(SH + 16384);

        const int i0 = (blockIdx.x & 63) * 128;
        const int j0 = (blockIdx.x >> 6) * 128;
        const int jj = (tid & 63) * 2;  // two consecutive j rows
        const int ih = tid >> 6;        // i-chunk of 32

        // BATCHED loads: all 32 row-loads issued into independent regs BEFORE any
        // packing, so ~32 vmem stay outstanding per wave (R6 was ~1 -> 2.1 TB/s).
        i32x2 av[32];
        const int* ap = adj + (size_t)(i0 + ih * 32) * N_NODES + j0 + jj;
#pragma unroll
        for (int r = 0; r < 32; ++r)
            av[r] = *(const i32x2*)(ap + (size_t)r * N_NODES);

        u32 pk[2][16];
        int d0 = 0, d1 = 0;
#pragma unroll
        for (int r = 0; r < 32; ++r) {
            d0 += av[r][0]; d1 += av[r][1];
            u32 b0 = (u32)av[r][0] * 0x3F80u;
            u32 b1 = (u32)av[r][1] * 0x3F80u;
            if ((r & 1) == 0) { pk[0][r >> 1] = b0;        pk[1][r >> 1] = b1; }
            else              { pk[0][r >> 1] |= b0 << 16; pk[1][r >> 1] |= b1 << 16; }
        }
#pragma unroll
        for (int p = 0; p < 2; ++p) {
            int row = jj + p;
#pragma unroll
            for (int c = 0; c < 4; ++c) {
                int ps = t_swz(row, ih * 4 + c);
                i32x4 w = {(int)pk[p][c * 4], (int)pk[p][c * 4 + 1],
                           (int)pk[p][c * 4 + 2], (int)pk[p][c * 4 + 3]};
                *(i32x4*)&T[row * 128 + ps * 8] = w;
            }
        }
        Dred[ih][jj] = d0;
        Dred[ih][jj + 1] = d1;
        __syncthreads();

#pragma unroll
        for (int rep = 0; rep < 8; ++rep) {
            int row = (tid >> 4) + rep * 16;
            int slot = tid & 15;
            int ps = t_swz(row, slot);
            i32x4 w = *(const i32x4*)&T[row * 128 + ps * 8];
            *(i32x4*)(At + (size_t)(j0 + row) * N_NODES + i0 + slot * 8) = w;
        }
        if (tid < 128) {
            int d = Dred[0][tid] + Dred[1][tid] + Dred[2][tid] + Dred[3][tid];
            atomicAdd(&deg[j0 + tid], d);
        }
        return;
    }

    // ---- k1: Yt[f][i] = bf16( sum_c W[c][f] * X[i][c] ) ----
    u16* Wl = SH;          // 128 x 64
    u16* Xl = SH + 8192;   // 128 x 64

    const int bid = blockIdx.x - 4096;
    const int lane = tid & 63;
    const int wave = tid >> 6;
    const int wm = wave >> 1, wn = wave & 1;
    const int col = lane & 15, quad = lane >> 4;

    const int f0 = (bid & 3) * 128;
    const int i0 = (bid >> 2) * 128;

    const int cgrp = tid & 31;
    const int kk   = tid >> 5;
    const int xcq  = tid & 15;
    const int xig  = tid >> 4;

    f32x4 wr[8], xr[8];
    {
        const float* wp = W + (size_t)(kk * 8) * F_DIM + f0 + cgrp * 4;
        const float* xp = X + (size_t)(i0 + xig * 8) * F_DIM + xcq * 4;
#pragma unroll
        for (int r = 0; r < 8; ++r) wr[r] = *(const f32x4*)(wp + (size_t)r * F_DIM);
#pragma unroll
        for (int r = 0; r < 8; ++r) xr[r] = *(const f32x4*)(xp + (size_t)r * F_DIM);
    }

    f32x4 acc[4][4] = {};

    for (int s = 0; s < 8; ++s) {
        BARRIER_NOVM();
#pragma unroll
        for (int mm = 0; mm < 4; ++mm) {
            int m = cgrp * 4 + mm;
            u32 q0 = ((u32)f2bf(wr[1][mm]) << 16) | f2bf(wr[0][mm]);
            u32 q1 = ((u32)f2bf(wr[3][mm]) << 16) | f2bf(wr[2][mm]);
            u32 q2 = ((u32)f2bf(wr[5][mm]) << 16) | f2bf(wr[4][mm]);
            u32 q3 = ((u32)f2bf(wr[7][mm]) << 16) | f2bf(wr[6][mm]);
            i32x4 v = {(int)q0, (int)q1, (int)q2, (int)q3};
            *(i32x4*)&Wl[m * 64 + ((kk ^ fm_swz(m)) << 3)] = v;
        }
#pragma unroll
        for (int r = 0; r < 8; ++r) {
            int row = xig * 8 + r;
            u32 a = ((u32)f2bf(xr[r][1]) << 16) | f2bf(xr[r][0]);
            u32 b = ((u32)f2bf(xr[r][3]) << 16) | f2bf(xr[r][2]);
            int kc = xcq >> 1, half = xcq & 1;
            i32x2 v = {(int)a, (int)b};
            *(i32x2*)&Xl[row * 64 + ((kc ^ (row & 7)) << 3) + half * 4] = v;
        }
        BARRIER_NOVM();
        if (s + 1 < 8) {
            int c0 = (s + 1) * 64;
            const float* wp = W + (size_t)(c0 + kk * 8) * F_DIM + f0 + cgrp * 4;
            const float* xp = X + (size_t)(i0 + xig * 8) * F_DIM + c0 + xcq * 4;
#pragma unroll
            for (int r = 0; r < 8; ++r) wr[r] = *(const f32x4*)(wp + (size_t)r * F_DIM);
#pragma unroll
            for (int r = 0; r < 8; ++r) xr[r] = *(const f32x4*)(xp + (size_t)r * F_DIM);
        }
#pragma unroll
        for (int s2 = 0; s2 < 2; ++s2) {
            s16x8 af[4], bfr[4];
#pragma unroll
            for (int mi = 0; mi < 4; ++mi) {
                int m = wm * 64 + mi * 16 + col;
                int kc = s2 * 4 + quad;
                af[mi] = *(const s16x8*)&Wl[m * 64 + ((kc ^ fm_swz(m)) << 3)];
            }
#pragma unroll
            for (int ni = 0; ni < 4; ++ni) {
                int rr = wn * 64 + ni * 16 + col;
                int kc = s2 * 4 + quad;
                bfr[ni] = *(const s16x8*)&Xl[rr * 64 + ((kc ^ (rr & 7)) << 3)];
            }
#pragma unroll
            for (int mi = 0; mi < 4; ++mi)
#pragma unroll
                for (int ni = 0; ni < 4; ++ni)
                    acc[mi][ni] = __builtin_amdgcn_mfma_f32_16x16x32_bf16(af[mi], bfr[ni],
                                                                          acc[mi][ni], 0, 0, 0);
        }
    }

#pragma unroll
    for (int mi = 0; mi < 4; ++mi)
#pragma unroll
        for (int r = 0; r < 4; ++r) {
            int f = f0 + wm * 64 + mi * 16 + quad * 4 + r;
#pragma unroll
            for (int ni = 0; ni < 4; ++ni) {
                int i = i0 + wn * 64 + ni * 16 + col;
                Yt[(size_t)f * N_NODES + i] = f2bf(acc[mi][ni][r]);
            }
        }
}

// ---------------- Kernel 2: bf16 GEMM (m97 clone): parts[kq][j][f] = sum adjT*Yt (bf16 out) ----------------
// 128x128 tile, BK=64, single-buffered 32 KB LDS, 2-barrier K-loop, K-split 4 -> 4 blocks/CU.
__global__ __launch_bounds__(256, 4)
void k2_gemm(const u16* __restrict__ At, const u16* __restrict__ Yt,
             u16* __restrict__ parts) {
    __shared__ __align__(16) u16 As[128 * 64];
    __shared__ __align__(16) u16 Bs[128 * 64];

    const int tid = threadIdx.x, lane = tid & 63, wave = tid >> 6;
    const int wm = wave >> 1, wn = wave & 1;
    const int col = lane & 15, quad = lane >> 4;

    // bid = f_idx*256 + kq*64 + stripe: all 16 (f,kq) blocks of a stripe share bid%8 (XCD L2)
    const int f_idx = blockIdx.x >> 8;
    const int kq = (blockIdx.x >> 6) & 3;
    const int stripe = blockIdx.x & 63;
    const int j0 = stripe * 128, f0 = f_idx * 128, ibase = kq * 2048;
    u16* __restrict__ part = parts + (size_t)kq * N_NODES * F_DIM;

    const int rowl = lane >> 3;
    const int kc = (lane & 7) ^ rowl;

    f32x4 acc[4][4] = {};

    for (int s = 0; s < 32; ++s) {
        const int ik = ibase + s * 64;
#pragma unroll
        for (int gg = 0; gg < 4; ++gg) {
            const int g = wave * 4 + gg;
            glds16(At + (size_t)(j0 + g * 8 + rowl) * N_NODES + ik + kc * 8, &As[g * 512]);
            glds16(Yt + (size_t)(f0 + g * 8 + rowl) * N_NODES + ik + kc * 8, &Bs[g * 512]);
        }
        __syncthreads();
#pragma unroll
        for (int s2 = 0; s2 < 2; ++s2) {
            s16x8 af[4], bfr[4];
#pragma unroll
            for (int mi = 0; mi < 4; ++mi) {
                int m = wm * 64 + mi * 16 + col;
                int k2i = s2 * 4 + quad;
                af[mi] = *(const s16x8*)&As[m * 64 + ((k2i ^ (m & 7)) << 3)];
            }
#pragma unroll
            for (int ni = 0; ni < 4; ++ni) {
                int rr = wn * 64 + ni * 16 + col;
                int k2i = s2 * 4 + quad;
                bfr[ni] = *(const s16x8*)&Bs[rr * 64 + ((k2i ^ (rr & 7)) << 3)];
            }
#pragma unroll
            for (int mi = 0; mi < 4; ++mi)
#pragma unroll
                for (int ni = 0; ni < 4; ++ni)
                    acc[mi][ni] = __builtin_amdgcn_mfma_f32_16x16x32_bf16(af[mi], bfr[ni],
                                                                          acc[mi][ni], 0, 0, 0);
        }
        __syncthreads();
    }

#pragma unroll
    for (int mi = 0; mi < 4; ++mi)
#pragma unroll
        for (int r = 0; r < 4; ++r) {
            int jl = wm * 64 + mi * 16 + quad * 4 + r;
            size_t ob = (size_t)(j0 + jl) * F_DIM + f0 + wn * 64;
#pragma unroll
            for (int ni = 0; ni < 4; ++ni)
                part[ob + ni * 16 + col] = f2bf(acc[mi][ni][r]);
        }
}

// ---------------- Kernel 3: out = relu( rsqrt(max(deg,1)) * sum4(parts) ) ----------------
__global__ __launch_bounds__(256, 4)
void k3b(const u16* __restrict__ parts, const int* __restrict__ deg,
         float* __restrict__ out) {
    int idx = blockIdx.x * 256 + threadIdx.x;  // 8 f per thread
    int j = idx >> 6;
    int c = (idx & 63) * 8;
    size_t off = (size_t)j * F_DIM + c;
    const size_t PS = (size_t)N_NODES * F_DIM;
    s16x8 a = *(const s16x8*)(parts + off);
    s16x8 b = *(const s16x8*)(parts + PS + off);
    s16x8 cc = *(const s16x8*)(parts + 2 * PS + off);
    s16x8 d = *(const s16x8*)(parts + 3 * PS + off);
    float nv = rsqrtf(fmaxf((float)deg[j], 1.0f));
    f32x4 v0, v1;
#pragma unroll
    for (int t = 0; t < 4; ++t) {
        float s = bf2f((u16)a[t]) + bf2f((u16)b[t]) + bf2f((u16)cc[t]) + bf2f((u16)d[t]);
        v0[t] = fmaxf(s * nv, 0.0f);
    }
#pragma unroll
    for (int t = 0; t < 4; ++t) {
        float s = bf2f((u16)a[4 + t]) + bf2f((u16)b[4 + t]) + bf2f((u16)cc[4 + t]) + bf2f((u16)d[4 + t]);
        v1[t] = fmaxf(s * nv, 0.0f);
    }
    *(f32x4*)(out + off) = v0;
    *(f32x4*)(out + off + 4) = v1;
}

extern "C" void kernel_launch(void* const* d_in, const int* in_sizes, int n_in,
                              void* d_out, int out_size, void* d_ws, size_t ws_size,
                              hipStream_t stream) {
    (void)in_sizes; (void)n_in; (void)out_size; (void)ws_size;
    const float* X = (const float*)d_in[0];
    const int* adj = (const int*)d_in[1];
    const float* W = (const float*)d_in[2];
    float* out = (float*)d_out;
    char* w = (char*)d_ws;

    // ws: At 128Mi | Yt 8Mi | parts(bf16 x4) 32Mi | deg 32K   (~168 MB)
    u16* At = (u16*)w;
    u16* Yt = (u16*)(w + ((size_t)128 << 20));
    u16* parts = (u16*)(w + ((size_t)136 << 20));
    int* deg = (int*)(w + ((size_t)168 << 20));

    kZ<<<dim3(8), dim3(256), 0, stream>>>(deg);
    kM<<<dim3(4352), dim3(256), 0, stream>>>(adj, X, W, At, Yt, deg);
    k2_gemm<<<dim3(1024), dim3(256), 0, stream>>>(At, Yt, parts);
    k3b<<<dim3(2048), dim3(256), 0, stream>>>(parts, deg, out);
}

// Round 8
// 489.551 us; speedup vs baseline: 1.0481x; 1.0464x over previous
//
#include <hip/hip_runtime.h>

typedef unsigned int u32;
typedef unsigned short u16;
typedef __attribute__((ext_vector_type(4))) float f32x4;
typedef __attribute__((ext_vector_type(4))) int i32x4;
typedef __attribute__((ext_vector_type(2))) int i32x2;
typedef __attribute__((ext_vector_type(8))) short s16x8;

#define N_NODES 8192
#define F_DIM 512
#define NWORDS 256  // 8192/32 i-words

#define BARRIER_NOVM() asm volatile("s_waitcnt lgkmcnt(0)\ns_barrier" ::: "memory")

__device__ __forceinline__ int fm_swz(int m) {
    return ((m >> 2) & 7) ^ ((m & 3) << 1);
}

__device__ __forceinline__ u16 f2bf(float x) {
    u32 u = __builtin_bit_cast(u32, x);
    u = (u + 0x7FFFu + ((u >> 16) & 1u)) >> 16;
    return (u16)u;
}

__device__ __forceinline__ float bf2f(u16 b) {
    u32 u = ((u32)b) << 16;
    return __builtin_bit_cast(float, u);
}

__device__ __forceinline__ void glds16(const u16* g, u16* l) {
    __builtin_amdgcn_global_load_lds((const __attribute__((address_space(1))) u32*)g,
                                     (__attribute__((address_space(3))) u32*)l, 16, 0, 0);
}

// ---------------- kZ: zero deg[8192] ----------------
__global__ __launch_bounds__(256) void kZ(int* __restrict__ deg) {
    i32x4 z = {0, 0, 0, 0};
    *(i32x4*)(deg + blockIdx.x * 1024 + threadIdx.x * 4) = z;
}

// ---------------- kM: bit-transpose (blocks 0..4095) + X@W (blocks 4096..4351) ----------------
// Transpose branch: Atw[w][j] bit r of word w = adj[w*32+r][j]. No LDS staging; stores are
// 512B-contiguous per wave. deg via popcount + LDS reduce + 1 atomic set per block.
__global__ __launch_bounds__(256, 4)
void kM(const int* __restrict__ adj, const float* __restrict__ X, const float* __restrict__ W,
        u32* __restrict__ Atw, u16* __restrict__ Yt, int* __restrict__ deg) {
    __shared__ __align__(16) u16 SH[16384 + 1024];  // 34 KB overlay (k1 tiles / Dred)

    const int tid = threadIdx.x;

    if (blockIdx.x < 4096) {
        int (*Dred)[128] = (int(*)[128])SH;

        const int i0 = (blockIdx.x & 63) * 128;
        const int j0 = (blockIdx.x >> 6) * 128;
        const int jj = (tid & 63) * 2;  // two consecutive j columns
        const int ih = tid >> 6;        // i-chunk of 32 (one output word)

        i32x2 av[32];
        const int* ap = adj + (size_t)(i0 + ih * 32) * N_NODES + j0 + jj;
#pragma unroll
        for (int r = 0; r < 32; ++r)
            av[r] = *(const i32x2*)(ap + (size_t)r * N_NODES);

        u32 b0 = 0, b1 = 0;
#pragma unroll
        for (int r = 0; r < 32; ++r) {
            b0 |= ((u32)av[r][0]) << r;
            b1 |= ((u32)av[r][1]) << r;
        }
        i32x2 bv = {(int)b0, (int)b1};
        *(i32x2*)(Atw + (size_t)(i0 / 32 + ih) * N_NODES + j0 + jj) = bv;

        Dred[ih][jj] = __popc(b0);
        Dred[ih][jj + 1] = __popc(b1);
        __syncthreads();
        if (tid < 128) {
            int d = Dred[0][tid] + Dred[1][tid] + Dred[2][tid] + Dred[3][tid];
            atomicAdd(&deg[j0 + tid], d);
        }
        return;
    }

    // ---- k1: Yt[f][i] = bf16( sum_c W[c][f] * X[i][c] ) ----
    u16* Wl = SH;          // 128 x 64
    u16* Xl = SH + 8192;   // 128 x 64

    const int bid = blockIdx.x - 4096;
    const int lane = tid & 63;
    const int wave = tid >> 6;
    const int wm = wave >> 1, wn = wave & 1;
    const int col = lane & 15, quad = lane >> 4;

    const int f0 = (bid & 3) * 128;
    const int i0 = (bid >> 2) * 128;

    const int cgrp = tid & 31;
    const int kk   = tid >> 5;
    const int xcq  = tid & 15;
    const int xig  = tid >> 4;

    f32x4 wr[8], xr[8];
    {
        const float* wp = W + (size_t)(kk * 8) * F_DIM + f0 + cgrp * 4;
        const float* xp = X + (size_t)(i0 + xig * 8) * F_DIM + xcq * 4;
#pragma unroll
        for (int r = 0; r < 8; ++r) wr[r] = *(const f32x4*)(wp + (size_t)r * F_DIM);
#pragma unroll
        for (int r = 0; r < 8; ++r) xr[r] = *(const f32x4*)(xp + (size_t)r * F_DIM);
    }

    f32x4 acc[4][4] = {};

    for (int s = 0; s < 8; ++s) {
        BARRIER_NOVM();
#pragma unroll
        for (int mm = 0; mm < 4; ++mm) {
            int m = cgrp * 4 + mm;
            u32 q0 = ((u32)f2bf(wr[1][mm]) << 16) | f2bf(wr[0][mm]);
            u32 q1 = ((u32)f2bf(wr[3][mm]) << 16) | f2bf(wr[2][mm]);
            u32 q2 = ((u32)f2bf(wr[5][mm]) << 16) | f2bf(wr[4][mm]);
            u32 q3 = ((u32)f2bf(wr[7][mm]) << 16) | f2bf(wr[6][mm]);
            i32x4 v = {(int)q0, (int)q1, (int)q2, (int)q3};
            *(i32x4*)&Wl[m * 64 + ((kk ^ fm_swz(m)) << 3)] = v;
        }
#pragma unroll
        for (int r = 0; r < 8; ++r) {
            int row = xig * 8 + r;
            u32 a = ((u32)f2bf(xr[r][1]) << 16) | f2bf(xr[r][0]);
            u32 b = ((u32)f2bf(xr[r][3]) << 16) | f2bf(xr[r][2]);
            int kc = xcq >> 1, half = xcq & 1;
            i32x2 v = {(int)a, (int)b};
            *(i32x2*)&Xl[row * 64 + ((kc ^ (row & 7)) << 3) + half * 4] = v;
        }
        BARRIER_NOVM();
        if (s + 1 < 8) {
            int c0 = (s + 1) * 64;
            const float* wp = W + (size_t)(c0 + kk * 8) * F_DIM + f0 + cgrp * 4;
            const float* xp = X + (size_t)(i0 + xig * 8) * F_DIM + c0 + xcq * 4;
#pragma unroll
            for (int r = 0; r < 8; ++r) wr[r] = *(const f32x4*)(wp + (size_t)r * F_DIM);
#pragma unroll
            for (int r = 0; r < 8; ++r) xr[r] = *(const f32x4*)(xp + (size_t)r * F_DIM);
        }
#pragma unroll
        for (int s2 = 0; s2 < 2; ++s2) {
            s16x8 af[4], bfr[4];
#pragma unroll
            for (int mi = 0; mi < 4; ++mi) {
                int m = wm * 64 + mi * 16 + col;
                int kc = s2 * 4 + quad;
                af[mi] = *(const s16x8*)&Wl[m * 64 + ((kc ^ fm_swz(m)) << 3)];
            }
#pragma unroll
            for (int ni = 0; ni < 4; ++ni) {
                int rr = wn * 64 + ni * 16 + col;
                int kc = s2 * 4 + quad;
                bfr[ni] = *(const s16x8*)&Xl[rr * 64 + ((kc ^ (rr & 7)) << 3)];
            }
#pragma unroll
            for (int mi = 0; mi < 4; ++mi)
#pragma unroll
                for (int ni = 0; ni < 4; ++ni)
                    acc[mi][ni] = __builtin_amdgcn_mfma_f32_16x16x32_bf16(af[mi], bfr[ni],
                                                                          acc[mi][ni], 0, 0, 0);
        }
    }

#pragma unroll
    for (int mi = 0; mi < 4; ++mi)
#pragma unroll
        for (int r = 0; r < 4; ++r) {
            int f = f0 + wm * 64 + mi * 16 + quad * 4 + r;
#pragma unroll
            for (int ni = 0; ni < 4; ++ni) {
                int i = i0 + wn * 64 + ni * 16 + col;
                Yt[(size_t)f * N_NODES + i] = f2bf(acc[mi][ni][r]);
            }
        }
}

// ---------------- Kernel 2: bf16 GEMM with in-loop A-bit expansion ----------------
// A-bits (1 KB/step) loaded 1 dword/thread, prefetched a step ahead; expanded to the
// 16 KB bf16 LDS A-tile inside the glds-B drain window. B staged via glds16 as before.
__global__ __launch_bounds__(256, 4)
void k2_gemm(const u32* __restrict__ Atw, const u16* __restrict__ Yt,
             u16* __restrict__ parts) {
    __shared__ __align__(16) u16 As[128 * 64];
    __shared__ __align__(16) u16 Bs[128 * 64];

    const int tid = threadIdx.x, lane = tid & 63, wave = tid >> 6;
    const int wm = wave >> 1, wn = wave & 1;
    const int col = lane & 15, quad = lane >> 4;

    const int f_idx = blockIdx.x >> 8;
    const int kq = (blockIdx.x >> 6) & 3;
    const int stripe = blockIdx.x & 63;
    const int j0 = stripe * 128, f0 = f_idx * 128, ibase = kq * 2048;
    u16* __restrict__ part = parts + (size_t)kq * N_NODES * F_DIM;

    const int rowl = lane >> 3;
    const int kc = (lane & 7) ^ rowl;

    const int m_up = tid & 127;   // unpack: j-row this thread owns
    const int sh   = tid >> 7;    // unpack: which of the 2 k-words

    f32x4 acc[4][4] = {};

    // prefetch step-0 A-bits word
    u32 r = Atw[(size_t)(kq * 64 + sh) * N_NODES + j0 + m_up];

    for (int s = 0; s < 32; ++s) {
        const int ik = ibase + s * 64;
        BARRIER_NOVM();  // all waves done with mfma(s-1); As/Bs free (lgkm only)
        // stage B tile (async DMA)
#pragma unroll
        for (int gg = 0; gg < 4; ++gg) {
            const int g = wave * 4 + gg;
            glds16(Yt + (size_t)(f0 + g * 8 + rowl) * N_NODES + ik + kc * 8, &Bs[g * 512]);
        }
        // expand A-bits -> bf16 LDS tile (VALU work fills the glds drain window)
        {
            u32 wv = r;
#pragma unroll
            for (int q = 0; q < 4; ++q) {
                u32 bb = (wv >> (q * 8)) & 0xFFu;
                u32 w0 = ((bb & 1u) * 0x3F80u) | ((bb & 2u) * 0x1FC00000u);
                u32 w1 = (((bb >> 2) & 1u) * 0x3F80u) | (((bb >> 2) & 2u) * 0x1FC00000u);
                u32 w2 = (((bb >> 4) & 1u) * 0x3F80u) | (((bb >> 4) & 2u) * 0x1FC00000u);
                u32 w3 = (((bb >> 6) & 1u) * 0x3F80u) | (((bb >> 6) & 2u) * 0x1FC00000u);
                int kcs = sh * 4 + q;
                i32x4 v = {(int)w0, (int)w1, (int)w2, (int)w3};
                *(i32x4*)&As[m_up * 64 + ((kcs ^ fm_swz(m_up)) << 3)] = v;
            }
        }
        // prefetch next step's A-bits word
        {
            int sn = (s + 1 < 32) ? (s + 1) : 31;
            r = Atw[(size_t)(kq * 64 + sn * 2 + sh) * N_NODES + j0 + m_up];
        }
        __syncthreads();  // drains glds (B ready) + lgkm (As writes visible)
#pragma unroll
        for (int s2 = 0; s2 < 2; ++s2) {
            s16x8 af[4], bfr[4];
#pragma unroll
            for (int mi = 0; mi < 4; ++mi) {
                int m = wm * 64 + mi * 16 + col;
                int k2i = s2 * 4 + quad;
                af[mi] = *(const s16x8*)&As[m * 64 + ((k2i ^ fm_swz(m)) << 3)];
            }
#pragma unroll
            for (int ni = 0; ni < 4; ++ni) {
                int rr = wn * 64 + ni * 16 + col;
                int k2i = s2 * 4 + quad;
                bfr[ni] = *(const s16x8*)&Bs[rr * 64 + ((k2i ^ (rr & 7)) << 3)];
            }
#pragma unroll
            for (int mi = 0; mi < 4; ++mi)
#pragma unroll
                for (int ni = 0; ni < 4; ++ni)
                    acc[mi][ni] = __builtin_amdgcn_mfma_f32_16x16x32_bf16(af[mi], bfr[ni],
                                                                          acc[mi][ni], 0, 0, 0);
        }
    }

#pragma unroll
    for (int mi = 0; mi < 4; ++mi)
#pragma unroll
        for (int r2 = 0; r2 < 4; ++r2) {
            int jl = wm * 64 + mi * 16 + quad * 4 + r2;
            size_t ob = (size_t)(j0 + jl) * F_DIM + f0 + wn * 64;
#pragma unroll
            for (int ni = 0; ni < 4; ++ni)
                part[ob + ni * 16 + col] = f2bf(acc[mi][ni][r2]);
        }
}

// ---------------- Kernel 3: out = relu( rsqrt(max(deg,1)) * sum4(parts) ) ----------------
__global__ __launch_bounds__(256, 4)
void k3b(const u16* __restrict__ parts, const int* __restrict__ deg,
         float* __restrict__ out) {
    int idx = blockIdx.x * 256 + threadIdx.x;  // 8 f per thread
    int j = idx >> 6;
    int c = (idx & 63) * 8;
    size_t off = (size_t)j * F_DIM + c;
    const size_t PS = (size_t)N_NODES * F_DIM;
    s16x8 a = *(const s16x8*)(parts + off);
    s16x8 b = *(const s16x8*)(parts + PS + off);
    s16x8 cc = *(const s16x8*)(parts + 2 * PS + off);
    s16x8 d = *(const s16x8*)(parts + 3 * PS + off);
    float nv = rsqrtf(fmaxf((float)deg[j], 1.0f));
    f32x4 v0, v1;
#pragma unroll
    for (int t = 0; t < 4; ++t) {
        float s = bf2f((u16)a[t]) + bf2f((u16)b[t]) + bf2f((u16)cc[t]) + bf2f((u16)d[t]);
        v0[t] = fmaxf(s * nv, 0.0f);
    }
#pragma unroll
    for (int t = 0; t < 4; ++t) {
        float s = bf2f((u16)a[4 + t]) + bf2f((u16)b[4 + t]) + bf2f((u16)cc[4 + t]) + bf2f((u16)d[4 + t]);
        v1[t] = fmaxf(s * nv, 0.0f);
    }
    *(f32x4*)(out + off) = v0;
    *(f32x4*)(out + off + 4) = v1;
}

extern "C" void kernel_launch(void* const* d_in, const int* in_sizes, int n_in,
                              void* d_out, int out_size, void* d_ws, size_t ws_size,
                              hipStream_t stream) {
    (void)in_sizes; (void)n_in; (void)out_size; (void)ws_size;
    const float* X = (const float*)d_in[0];
    const int* adj = (const int*)d_in[1];
    const float* W = (const float*)d_in[2];
    float* out = (float*)d_out;
    char* w = (char*)d_ws;

    // ws: Atw(bits) 8Mi | Yt 8Mi | parts(bf16 x4) 32Mi | deg 32K
    u32* Atw = (u32*)w;
    u16* Yt = (u16*)(w + ((size_t)8 << 20));
    u16* parts = (u16*)(w + ((size_t)16 << 20));
    int* deg = (int*)(w + ((size_t)48 << 20));

    kZ<<<dim3(8), dim3(256), 0, stream>>>(deg);
    kM<<<dim3(4352), dim3(256), 0, stream>>>(adj, X, W, Atw, Yt, deg);
    k2_gemm<<<dim3(1024), dim3(256), 0, stream>>>(Atw, Yt, parts);
    k3b<<<dim3(2048), dim3(256), 0, stream>>>(parts, deg, out);
}

// Round 9
// 481.938 us; speedup vs baseline: 1.0647x; 1.0158x over previous
//
#include <hip/hip_runtime.h>

typedef unsigned int u32;
typedef unsigned short u16;
typedef __attribute__((ext_vector_type(4))) float f32x4;
typedef __attribute__((ext_vector_type(4))) int i32x4;
typedef __attribute__((ext_vector_type(2))) int i32x2;
typedef __attribute__((ext_vector_type(8))) short s16x8;

#define N_NODES 8192
#define F_DIM 512

#define BARRIER_NOVM() asm volatile("s_waitcnt lgkmcnt(0)\ns_barrier" ::: "memory")

__device__ __forceinline__ int fm_swz(int m) {
    return ((m >> 2) & 7) ^ ((m & 3) << 1);
}

__device__ __forceinline__ u16 f2bf(float x) {
    u32 u = __builtin_bit_cast(u32, x);
    u = (u + 0x7FFFu + ((u >> 16) & 1u)) >> 16;
    return (u16)u;
}

__device__ __forceinline__ float bf2f(u16 b) {
    u32 u = ((u32)b) << 16;
    return __builtin_bit_cast(float, u);
}

__device__ __forceinline__ void glds16(const u16* g, u16* l) {
    __builtin_amdgcn_global_load_lds((const __attribute__((address_space(1))) u32*)g,
                                     (__attribute__((address_space(3))) u32*)l, 16, 0, 0);
}

// ---------------- kM: bit-transpose (blocks 0..255, row-contiguous reads) + X@W (256..511) ----------------
// Transpose: block b owns i-word w=b (rows w*32..w*32+31). Each row is read IN FULL:
// 8 chunks x (64 lanes x 16B contiguous) = 32 KB sequential -> no strided channel camping.
// Thread owns j = q*1024 + tid*4 + e; bit r ORed via one v_lshl_or per element.
__global__ __launch_bounds__(256, 4)
void kM(const int* __restrict__ adj, const float* __restrict__ X, const float* __restrict__ W,
        u32* __restrict__ Atw, u16* __restrict__ Yt) {
    __shared__ __align__(16) u16 SH[16384];  // used by k1 branch only

    const int tid = threadIdx.x;

    if (blockIdx.x < 256) {
        const int w = blockIdx.x;
        const int* base = adj + (size_t)w * 32 * N_NODES;

        u32 wacc[8][4] = {};
        i32x4 cur[8], nxt[8];

#pragma unroll
        for (int q = 0; q < 8; ++q)
            cur[q] = *(const i32x4*)(base + q * 1024 + tid * 4);

        for (int r = 0; r < 32; r += 2) {
            const int* rp1 = base + (size_t)(r + 1) * N_NODES;
#pragma unroll
            for (int q = 0; q < 8; ++q)
                nxt[q] = *(const i32x4*)(rp1 + q * 1024 + tid * 4);
#pragma unroll
            for (int q = 0; q < 8; ++q)
#pragma unroll
                for (int e = 0; e < 4; ++e)
                    wacc[q][e] |= ((u32)cur[q][e]) << r;
            if (r + 2 < 32) {
                const int* rp2 = base + (size_t)(r + 2) * N_NODES;
#pragma unroll
                for (int q = 0; q < 8; ++q)
                    cur[q] = *(const i32x4*)(rp2 + q * 1024 + tid * 4);
            }
#pragma unroll
            for (int q = 0; q < 8; ++q)
#pragma unroll
                for (int e = 0; e < 4; ++e)
                    wacc[q][e] |= ((u32)nxt[q][e]) << (r + 1);
        }

        u32* orow = Atw + (size_t)w * N_NODES;
#pragma unroll
        for (int q = 0; q < 8; ++q) {
            i32x4 v = {(int)wacc[q][0], (int)wacc[q][1], (int)wacc[q][2], (int)wacc[q][3]};
            *(i32x4*)(orow + q * 1024 + tid * 4) = v;
        }
        return;
    }

    // ---- k1: Yt[f][i] = bf16( sum_c W[c][f] * X[i][c] ) ----
    u16* Wl = SH;          // 128 x 64
    u16* Xl = SH + 8192;   // 128 x 64

    const int bid = blockIdx.x - 256;
    const int lane = tid & 63;
    const int wave = tid >> 6;
    const int wm = wave >> 1, wn = wave & 1;
    const int col = lane & 15, quad = lane >> 4;

    const int f0 = (bid & 3) * 128;
    const int i0 = (bid >> 2) * 128;

    const int cgrp = tid & 31;
    const int kk   = tid >> 5;
    const int xcq  = tid & 15;
    const int xig  = tid >> 4;

    f32x4 wr[8], xr[8];
    {
        const float* wp = W + (size_t)(kk * 8) * F_DIM + f0 + cgrp * 4;
        const float* xp = X + (size_t)(i0 + xig * 8) * F_DIM + xcq * 4;
#pragma unroll
        for (int r = 0; r < 8; ++r) wr[r] = *(const f32x4*)(wp + (size_t)r * F_DIM);
#pragma unroll
        for (int r = 0; r < 8; ++r) xr[r] = *(const f32x4*)(xp + (size_t)r * F_DIM);
    }

    f32x4 acc[4][4] = {};

    for (int s = 0; s < 8; ++s) {
        BARRIER_NOVM();
#pragma unroll
        for (int mm = 0; mm < 4; ++mm) {
            int m = cgrp * 4 + mm;
            u32 q0 = ((u32)f2bf(wr[1][mm]) << 16) | f2bf(wr[0][mm]);
            u32 q1 = ((u32)f2bf(wr[3][mm]) << 16) | f2bf(wr[2][mm]);
            u32 q2 = ((u32)f2bf(wr[5][mm]) << 16) | f2bf(wr[4][mm]);
            u32 q3 = ((u32)f2bf(wr[7][mm]) << 16) | f2bf(wr[6][mm]);
            i32x4 v = {(int)q0, (int)q1, (int)q2, (int)q3};
            *(i32x4*)&Wl[m * 64 + ((kk ^ fm_swz(m)) << 3)] = v;
        }
#pragma unroll
        for (int r = 0; r < 8; ++r) {
            int row = xig * 8 + r;
            u32 a = ((u32)f2bf(xr[r][1]) << 16) | f2bf(xr[r][0]);
            u32 b = ((u32)f2bf(xr[r][3]) << 16) | f2bf(xr[r][2]);
            int kc = xcq >> 1, half = xcq & 1;
            i32x2 v = {(int)a, (int)b};
            *(i32x2*)&Xl[row * 64 + ((kc ^ (row & 7)) << 3) + half * 4] = v;
        }
        BARRIER_NOVM();
        if (s + 1 < 8) {
            int c0 = (s + 1) * 64;
            const float* wp = W + (size_t)(c0 + kk * 8) * F_DIM + f0 + cgrp * 4;
            const float* xp = X + (size_t)(i0 + xig * 8) * F_DIM + c0 + xcq * 4;
#pragma unroll
            for (int r = 0; r < 8; ++r) wr[r] = *(const f32x4*)(wp + (size_t)r * F_DIM);
#pragma unroll
            for (int r = 0; r < 8; ++r) xr[r] = *(const f32x4*)(xp + (size_t)r * F_DIM);
        }
#pragma unroll
        for (int s2 = 0; s2 < 2; ++s2) {
            s16x8 af[4], bfr[4];
#pragma unroll
            for (int mi = 0; mi < 4; ++mi) {
                int m = wm * 64 + mi * 16 + col;
                int kc = s2 * 4 + quad;
                af[mi] = *(const s16x8*)&Wl[m * 64 + ((kc ^ fm_swz(m)) << 3)];
            }
#pragma unroll
            for (int ni = 0; ni < 4; ++ni) {
                int rr = wn * 64 + ni * 16 + col;
                int kc = s2 * 4 + quad;
                bfr[ni] = *(const s16x8*)&Xl[rr * 64 + ((kc ^ (rr & 7)) << 3)];
            }
#pragma unroll
            for (int mi = 0; mi < 4; ++mi)
#pragma unroll
                for (int ni = 0; ni < 4; ++ni)
                    acc[mi][ni] = __builtin_amdgcn_mfma_f32_16x16x32_bf16(af[mi], bfr[ni],
                                                                          acc[mi][ni], 0, 0, 0);
        }
    }

#pragma unroll
    for (int mi = 0; mi < 4; ++mi)
#pragma unroll
        for (int r = 0; r < 4; ++r) {
            int f = f0 + wm * 64 + mi * 16 + quad * 4 + r;
#pragma unroll
            for (int ni = 0; ni < 4; ++ni) {
                int i = i0 + wn * 64 + ni * 16 + col;
                Yt[(size_t)f * N_NODES + i] = f2bf(acc[mi][ni][r]);
            }
        }
}

// ---------------- kD: deg[j] = sum_w popc(Atw[w][j]) (no atomics, no pre-zero) ----------------
__global__ __launch_bounds__(256, 8)
void kD(const u32* __restrict__ Atw, int* __restrict__ deg) {
    const int j = blockIdx.x * 256 + threadIdx.x;
    int s = 0;
#pragma unroll 8
    for (int w = 0; w < 256; ++w)
        s += __popc(Atw[(size_t)w * N_NODES + j]);
    deg[j] = s;
}

// ---------------- Kernel 2: bf16 GEMM with in-loop A-bit expansion ----------------
__global__ __launch_bounds__(256, 4)
void k2_gemm(const u32* __restrict__ Atw, const u16* __restrict__ Yt,
             u16* __restrict__ parts) {
    __shared__ __align__(16) u16 As[128 * 64];
    __shared__ __align__(16) u16 Bs[128 * 64];

    const int tid = threadIdx.x, lane = tid & 63, wave = tid >> 6;
    const int wm = wave >> 1, wn = wave & 1;
    const int col = lane & 15, quad = lane >> 4;

    const int f_idx = blockIdx.x >> 8;
    const int kq = (blockIdx.x >> 6) & 3;
    const int stripe = blockIdx.x & 63;
    const int j0 = stripe * 128, f0 = f_idx * 128, ibase = kq * 2048;
    u16* __restrict__ part = parts + (size_t)kq * N_NODES * F_DIM;

    const int rowl = lane >> 3;
    const int kc = (lane & 7) ^ rowl;

    const int m_up = tid & 127;   // unpack: j-row this thread owns
    const int sh   = tid >> 7;    // unpack: which of the 2 k-words

    f32x4 acc[4][4] = {};

    u32 r = Atw[(size_t)(kq * 64 + sh) * N_NODES + j0 + m_up];

    for (int s = 0; s < 32; ++s) {
        const int ik = ibase + s * 64;
        BARRIER_NOVM();  // all waves done with mfma(s-1); As/Bs free (lgkm only)
#pragma unroll
        for (int gg = 0; gg < 4; ++gg) {
            const int g = wave * 4 + gg;
            glds16(Yt + (size_t)(f0 + g * 8 + rowl) * N_NODES + ik + kc * 8, &Bs[g * 512]);
        }
        {
            u32 wv = r;
#pragma unroll
            for (int q = 0; q < 4; ++q) {
                u32 bb = (wv >> (q * 8)) & 0xFFu;
                u32 w0 = ((bb & 1u) * 0x3F80u) | ((bb & 2u) * 0x1FC00000u);
                u32 w1 = (((bb >> 2) & 1u) * 0x3F80u) | (((bb >> 2) & 2u) * 0x1FC00000u);
                u32 w2 = (((bb >> 4) & 1u) * 0x3F80u) | (((bb >> 4) & 2u) * 0x1FC00000u);
                u32 w3 = (((bb >> 6) & 1u) * 0x3F80u) | (((bb >> 6) & 2u) * 0x1FC00000u);
                int kcs = sh * 4 + q;
                i32x4 v = {(int)w0, (int)w1, (int)w2, (int)w3};
                *(i32x4*)&As[m_up * 64 + ((kcs ^ fm_swz(m_up)) << 3)] = v;
            }
        }
        {
            int sn = (s + 1 < 32) ? (s + 1) : 31;
            r = Atw[(size_t)(kq * 64 + sn * 2 + sh) * N_NODES + j0 + m_up];
        }
        __syncthreads();  // drains glds (B ready) + lgkm (As writes visible)
#pragma unroll
        for (int s2 = 0; s2 < 2; ++s2) {
            s16x8 af[4], bfr[4];
#pragma unroll
            for (int mi = 0; mi < 4; ++mi) {
                int m = wm * 64 + mi * 16 + col;
                int k2i = s2 * 4 + quad;
                af[mi] = *(const s16x8*)&As[m * 64 + ((k2i ^ fm_swz(m)) << 3)];
            }
#pragma unroll
            for (int ni = 0; ni < 4; ++ni) {
                int rr = wn * 64 + ni * 16 + col;
                int k2i = s2 * 4 + quad;
                bfr[ni] = *(const s16x8*)&Bs[rr * 64 + ((k2i ^ (rr & 7)) << 3)];
            }
#pragma unroll
            for (int mi = 0; mi < 4; ++mi)
#pragma unroll
                for (int ni = 0; ni < 4; ++ni)
                    acc[mi][ni] = __builtin_amdgcn_mfma_f32_16x16x32_bf16(af[mi], bfr[ni],
                                                                          acc[mi][ni], 0, 0, 0);
        }
    }

#pragma unroll
    for (int mi = 0; mi < 4; ++mi)
#pragma unroll
        for (int r2 = 0; r2 < 4; ++r2) {
            int jl = wm * 64 + mi * 16 + quad * 4 + r2;
            size_t ob = (size_t)(j0 + jl) * F_DIM + f0 + wn * 64;
#pragma unroll
            for (int ni = 0; ni < 4; ++ni)
                part[ob + ni * 16 + col] = f2bf(acc[mi][ni][r2]);
        }
}

// ---------------- Kernel 3: out = relu( rsqrt(max(deg,1)) * sum4(parts) ) ----------------
__global__ __launch_bounds__(256, 4)
void k3b(const u16* __restrict__ parts, const int* __restrict__ deg,
         float* __restrict__ out) {
    int idx = blockIdx.x * 256 + threadIdx.x;  // 8 f per thread
    int j = idx >> 6;
    int c = (idx & 63) * 8;
    size_t off = (size_t)j * F_DIM + c;
    const size_t PS = (size_t)N_NODES * F_DIM;
    s16x8 a = *(const s16x8*)(parts + off);
    s16x8 b = *(const s16x8*)(parts + PS + off);
    s16x8 cc = *(const s16x8*)(parts + 2 * PS + off);
    s16x8 d = *(const s16x8*)(parts + 3 * PS + off);
    float nv = rsqrtf(fmaxf((float)deg[j], 1.0f));
    f32x4 v0, v1;
#pragma unroll
    for (int t = 0; t < 4; ++t) {
        float s = bf2f((u16)a[t]) + bf2f((u16)b[t]) + bf2f((u16)cc[t]) + bf2f((u16)d[t]);
        v0[t] = fmaxf(s * nv, 0.0f);
    }
#pragma unroll
    for (int t = 0; t < 4; ++t) {
        float s = bf2f((u16)a[4 + t]) + bf2f((u16)b[4 + t]) + bf2f((u16)cc[4 + t]) + bf2f((u16)d[4 + t]);
        v1[t] = fmaxf(s * nv, 0.0f);
    }
    *(f32x4*)(out + off) = v0;
    *(f32x4*)(out + off + 4) = v1;
}

extern "C" void kernel_launch(void* const* d_in, const int* in_sizes, int n_in,
                              void* d_out, int out_size, void* d_ws, size_t ws_size,
                              hipStream_t stream) {
    (void)in_sizes; (void)n_in; (void)out_size; (void)ws_size;
    const float* X = (const float*)d_in[0];
    const int* adj = (const int*)d_in[1];
    const float* W = (const float*)d_in[2];
    float* out = (float*)d_out;
    char* w = (char*)d_ws;

    // ws: Atw(bits) 8Mi | Yt 8Mi | parts(bf16 x4) 32Mi | deg 32K
    u32* Atw = (u32*)w;
    u16* Yt = (u16*)(w + ((size_t)8 << 20));
    u16* parts = (u16*)(w + ((size_t)16 << 20));
    int* deg = (int*)(w + ((size_t)48 << 20));

    kM<<<dim3(512), dim3(256), 0, stream>>>(adj, X, W, Atw, Yt);
    kD<<<dim3(32), dim3(256), 0, stream>>>(Atw, deg);
    k2_gemm<<<dim3(1024), dim3(256), 0, stream>>>(Atw, Yt, parts);
    k3b<<<dim3(2048), dim3(256), 0, stream>>>(parts, deg, out);
}